// Round 1
// baseline (145.883 us; speedup 1.0000x reference)
//
#include <hip/hip_runtime.h>

// Problem constants (fixed by setup_inputs)
#define NB  8     // batch
#define SS  500   // seq
#define UU  128   // units (also GH*GD)
#define NG  5     // ngrams per chunk
#define CC  100   // chunks = S/NG
#define PP  10    // C(5,2) pairs
#define FF  20    // 2*PP edge-concat feature width
#define HH  5     // per-chunk heads
#define HD  10    // HH * DK (DK=2)
#define GHH 4     // graph heads
#define GDD 32    // graph head dim

// ---------------------------------------------------------------------------
// K1: per-chunk edge MHA + leaky_relu + mean + pos  ->  g  (written to d_out)
//     fused graph qkv projection  ->  gq/gk/gv (workspace)
// block = (b,c), thread = u in [0,128)
// ---------------------------------------------------------------------------
__global__ __launch_bounds__(128) void k1_chunk_mha(
    const float* __restrict__ x,   const float* __restrict__ wq,
    const float* __restrict__ bq,  const float* __restrict__ wk,
    const float* __restrict__ bk,  const float* __restrict__ wv,
    const float* __restrict__ bv,  const float* __restrict__ wo,
    const float* __restrict__ bo,  const float* __restrict__ pos,
    const float* __restrict__ gwq, const float* __restrict__ gbq,
    const float* __restrict__ gwk, const float* __restrict__ gbk,
    const float* __restrict__ gwv, const float* __restrict__ gbv,
    float* __restrict__ g_out, float* __restrict__ gq_out,
    float* __restrict__ gk_out, float* __restrict__ gv_out)
{
    const int bc = blockIdx.x;
    const int b  = bc / CC, c = bc % CC;
    const int u  = threadIdx.x;

    __shared__ float4 s_kv[UU][HH];   // (k0,k1,v0,v1) per (seq pos, head)
    __shared__ float  s_g[UU];

    // ---- load the 5 ngram values for this (b,c,u); build 20 edge features
    float xv[NG];
    const float* xb = x + (size_t)b * SS * UU + (size_t)c * NG * UU + u;
#pragma unroll
    for (int t = 0; t < NG; ++t) xv[t] = xb[t * UU];   // coalesced across u

    const int II[PP] = {0,0,0,0,1,1,1,2,2,3};
    const int JJ[PP] = {1,2,3,4,2,3,4,3,4,4};
    float ht[FF];
#pragma unroll
    for (int p = 0; p < PP; ++p) { ht[2*p] = xv[II[p]]; ht[2*p+1] = xv[JJ[p]]; }

    // ---- qkv projection; weight indices are block-uniform -> scalar loads
    const float* wqc = wq + c * (FF * HD);
    const float* wkc = wk + c * (FF * HD);
    const float* wvc = wv + c * (FF * HD);
    float qv[HD], kv[HD], vv[HD];
#pragma unroll
    for (int hd = 0; hd < HD; ++hd) {
        qv[hd] = bq[c*HD + hd]; kv[hd] = bk[c*HD + hd]; vv[hd] = bv[c*HD + hd];
    }
#pragma unroll
    for (int f = 0; f < FF; ++f) {
        const float hf = ht[f];
#pragma unroll
        for (int hd = 0; hd < HD; ++hd) {
            qv[hd] = fmaf(hf, wqc[f*HD + hd], qv[hd]);
            kv[hd] = fmaf(hf, wkc[f*HD + hd], kv[hd]);
            vv[hd] = fmaf(hf, wvc[f*HD + hd], vv[hd]);
        }
    }
#pragma unroll
    for (int h = 0; h < HH; ++h)
        s_kv[u][h] = make_float4(kv[2*h], kv[2*h+1], vv[2*h], vv[2*h+1]);
    __syncthreads();

    // ---- attention over v (seq = U). Scores are O(0.1): exact softmax
    //      without max-shift (shift-invariant; overflow impossible here).
    const float scale = 0.7071067811865476f;   // 1/sqrt(dk=2), applied to q
    float q0[HH], q1[HH], l[HH], o0[HH], o1[HH];
#pragma unroll
    for (int h = 0; h < HH; ++h) {
        q0[h] = qv[2*h] * scale; q1[h] = qv[2*h+1] * scale;
        l[h] = 0.f; o0[h] = 0.f; o1[h] = 0.f;
    }
#pragma unroll 2
    for (int vi = 0; vi < UU; ++vi) {
#pragma unroll
        for (int h = 0; h < HH; ++h) {
            const float4 kvv = s_kv[vi][h];          // one ds_read_b128 (broadcast)
            const float s = fmaf(q0[h], kvv.x, q1[h] * kvv.y);
            const float e = __expf(s);
            l[h]  += e;
            o0[h]  = fmaf(e, kvv.z, o0[h]);
            o1[h]  = fmaf(e, kvv.w, o1[h]);
        }
    }
    float o[HD];
#pragma unroll
    for (int h = 0; h < HH; ++h) {
        const float inv = 1.f / l[h];
        o[2*h] = o0[h] * inv; o[2*h+1] = o1[h] * inv;
    }

    // ---- output projection + residual + leaky_relu(0.3) + mean over F
    const float* woc = wo + c * (HD * FF);
    float gsum = 0.f;
#pragma unroll
    for (int f = 0; f < FF; ++f) {
        float acc = bo[c*FF + f];
#pragma unroll
        for (int hd = 0; hd < HD; ++hd) acc = fmaf(o[hd], woc[hd*FF + f], acc);
        const float a = ht[f] + acc;
        gsum += (a > 0.f) ? a : 0.3f * a;
    }
    const float g = gsum * (1.f / FF) + pos[c*UU + u];
    g_out[(size_t)bc*UU + u] = g;
    s_g[u] = g;
    __syncthreads();

    // ---- fused graph qkv projection: thread u computes feature hd = u
    const float gscale = 0.17677669529663687f;   // 1/sqrt(32)
    float aq = gbq[u], ak = gbk[u], av = gbv[u];
    for (int u2 = 0; u2 < UU; ++u2) {
        const float gu = s_g[u2];                 // LDS broadcast
        aq = fmaf(gu, gwq[u2*UU + u], aq);        // coalesced across u
        ak = fmaf(gu, gwk[u2*UU + u], ak);
        av = fmaf(gu, gwv[u2*UU + u], av);
    }
    gq_out[(size_t)bc*UU + u] = aq * gscale;
    gk_out[(size_t)bc*UU + u] = ak;
    gv_out[(size_t)bc*UU + u] = av;
}

// ---------------------------------------------------------------------------
// K2: graph attention per (b, head). go is written onto the gq buffer
//     (same (b,h) slice; all reads complete before __syncthreads).
// block = (b,h), thread = q row (t < 100 active)
// ---------------------------------------------------------------------------
__global__ __launch_bounds__(128) void k2_graph_attn(
    const float* gq, const float* __restrict__ gk,
    const float* __restrict__ gv, float* go)
{
    const int b = blockIdx.x / GHH, h = blockIdx.x % GHH;
    const int t = threadIdx.x;
    __shared__ float4 s_k[CC][GDD/4], s_v[CC][GDD/4];

    const float4* gk4 = (const float4*)(gk + (size_t)b * CC * UU);
    const float4* gv4 = (const float4*)(gv + (size_t)b * CC * UU);
    for (int idx = t; idx < CC * 8; idx += 128) {
        const int k = idx >> 3, d4 = idx & 7;
        s_k[k][d4] = gk4[k*32 + h*8 + d4];
        s_v[k][d4] = gv4[k*32 + h*8 + d4];
    }
    float4 qf[8];
    if (t < CC) {
        const float4* q4 = (const float4*)(gq + (size_t)b*CC*UU + (size_t)t*UU + h*GDD);
#pragma unroll
        for (int i = 0; i < 8; ++i) qf[i] = q4[i];
    }
    __syncthreads();

    if (t < CC) {
        float l = 0.f;
        float4 o[8];
#pragma unroll
        for (int i = 0; i < 8; ++i) o[i] = make_float4(0.f, 0.f, 0.f, 0.f);
        for (int k = 0; k < CC; ++k) {
            float s = 0.f;
#pragma unroll
            for (int i = 0; i < 8; ++i) {
                const float4 kf = s_k[k][i];
                s = fmaf(qf[i].x, kf.x, s); s = fmaf(qf[i].y, kf.y, s);
                s = fmaf(qf[i].z, kf.z, s); s = fmaf(qf[i].w, kf.w, s);
            }
            const float e = __expf(s);   // scores tiny; shift-free is exact
            l += e;
#pragma unroll
            for (int i = 0; i < 8; ++i) {
                const float4 vf = s_v[k][i];
                o[i].x = fmaf(e, vf.x, o[i].x); o[i].y = fmaf(e, vf.y, o[i].y);
                o[i].z = fmaf(e, vf.z, o[i].z); o[i].w = fmaf(e, vf.w, o[i].w);
            }
        }
        const float inv = 1.f / l;
        float4* go4 = (float4*)(go + (size_t)b*CC*UU + (size_t)t*UU + h*GDD);
#pragma unroll
        for (int i = 0; i < 8; ++i) {
            o[i].x *= inv; o[i].y *= inv; o[i].z *= inv; o[i].w *= inv;
            go4[i] = o[i];
        }
    }
}

// ---------------------------------------------------------------------------
// K3: out[b,q,u] = g[b,q,u] + sum_hd go[b,q,hd] * gwo[hd,u] + gbo[u]
// block = (b,q), thread = u
// ---------------------------------------------------------------------------
__global__ __launch_bounds__(128) void k3_out(
    const float* __restrict__ go, const float* __restrict__ gwo,
    const float* __restrict__ gbo, float* out)
{
    const int bq = blockIdx.x;
    const int u  = threadIdx.x;
    __shared__ float s_go[UU];
    s_go[u] = go[(size_t)bq*UU + u];
    __syncthreads();
    float acc = gbo[u];
    for (int hd = 0; hd < UU; ++hd)
        acc = fmaf(s_go[hd], gwo[hd*UU + u], acc);   // gwo coalesced across u
    out[(size_t)bq*UU + u] += acc;                   // d_out already holds g
}

extern "C" void kernel_launch(void* const* d_in, const int* in_sizes, int n_in,
                              void* d_out, int out_size, void* d_ws, size_t ws_size,
                              hipStream_t stream)
{
    (void)in_sizes; (void)n_in; (void)out_size; (void)ws_size;
    const float* x   = (const float*)d_in[0];
    const float* wq  = (const float*)d_in[1];
    const float* bq  = (const float*)d_in[2];
    const float* wk  = (const float*)d_in[3];
    const float* bk  = (const float*)d_in[4];
    const float* wv  = (const float*)d_in[5];
    const float* bv  = (const float*)d_in[6];
    const float* wo  = (const float*)d_in[7];
    const float* bo  = (const float*)d_in[8];
    const float* pos = (const float*)d_in[9];
    const float* gwq = (const float*)d_in[10];
    const float* gbq = (const float*)d_in[11];
    const float* gwk = (const float*)d_in[12];
    const float* gbk = (const float*)d_in[13];
    const float* gwv = (const float*)d_in[14];
    const float* gbv = (const float*)d_in[15];
    const float* gwo = (const float*)d_in[16];
    const float* gbo = (const float*)d_in[17];
    float* out = (float*)d_out;
    float* ws  = (float*)d_ws;

    float* gq_ws = ws;              // [8*100*128] — reused as go by K2
    float* gk_ws = ws + 102400;
    float* gv_ws = ws + 204800;

    k1_chunk_mha<<<NB*CC, 128, 0, stream>>>(x, wq, bq, wk, bk, wv, bv, wo, bo,
        pos, gwq, gbq, gwk, gbk, gwv, gbv, out, gq_ws, gk_ws, gv_ws);
    k2_graph_attn<<<NB*GHH, 128, 0, stream>>>(gq_ws, gk_ws, gv_ws, gq_ws);
    k3_out<<<NB*CC, 128, 0, stream>>>(gq_ws, gwo, gbo, out);
}